// Round 1
// baseline (20786.453 us; speedup 1.0000x reference)
//
#include <hip/hip_runtime.h>
#include <hip/hip_bf16.h>
#include <math.h>

// Problem constants
constexpr int NLAYER = 6;
constexpr int B_ = 2;
constexpr int L_ = 1024;
constexpr int D_ = 1024;
constexpr int H_ = 16;
constexpr int DH_ = 64;
constexpr int V_ = 30000;
constexpr int HID_ = 512;
constexpr int BL_ = B_ * L_;          // 2048 token rows

// ---------------------------------------------------------------------------
// helpers
// ---------------------------------------------------------------------------
__device__ __forceinline__ float sigmoidf_(float z) { return 1.0f / (1.0f + expf(-z)); }
__device__ __forceinline__ float gelu_exact_(float z) {
    return 0.5f * z * (1.0f + erff(z * 0.70710678118654752440f));
}

// block-wide reductions, blockDim.x == 256, `red` is shared float[256]
__device__ __forceinline__ float block_sum_(float v, float* red) {
    int tid = threadIdx.x;
    red[tid] = v; __syncthreads();
    #pragma unroll
    for (int s = 128; s > 0; s >>= 1) {
        if (tid < s) red[tid] += red[tid + s];
        __syncthreads();
    }
    float r = red[0];
    __syncthreads();
    return r;
}
__device__ __forceinline__ float block_max_(float v, float* red) {
    int tid = threadIdx.x;
    red[tid] = v; __syncthreads();
    #pragma unroll
    for (int s = 128; s > 0; s >>= 1) {
        if (tid < s) red[tid] = fmaxf(red[tid], red[tid + s]);
        __syncthreads();
    }
    float r = red[0];
    __syncthreads();
    return r;
}

// ---------------------------------------------------------------------------
// x = embed[ids]*sqrt(D) + pos_enc   (one block per token row)
// ---------------------------------------------------------------------------
__global__ __launch_bounds__(256) void embed_k(
    const int* __restrict__ ids, const float* __restrict__ emb,
    const float* __restrict__ pos, float* __restrict__ x)
{
    int t = blockIdx.x, tid = threadIdx.x;
    int id = ids[t];
    int l = t % L_;
    #pragma unroll
    for (int it = 0; it < 4; ++it) {
        int d = it * 256 + tid;
        x[(size_t)t * D_ + d] = emb[(size_t)id * D_ + d] * 32.0f + pos[(size_t)l * D_ + d];
    }
}

// ---------------------------------------------------------------------------
// fused: rg = sigmoid(x@rg_w + rg_b); store gs; xm = x*(1+0.1*mean(rg));
//        a_in = LayerNorm(xm, n1_g, n1_b).   One block per token row.
// ---------------------------------------------------------------------------
__global__ __launch_bounds__(256) void rg_xm_ln_k(
    const float* __restrict__ x, const float* __restrict__ rgw,
    const float* __restrict__ rgb, const float* __restrict__ g,
    const float* __restrict__ b, float* __restrict__ xm,
    float* __restrict__ ain, float* __restrict__ gs_out)
{
    int t = blockIdx.x, tid = threadIdx.x;
    __shared__ float xr[D_];
    __shared__ float red[256];
    __shared__ float rgsh[4];

    #pragma unroll
    for (int it = 0; it < 4; ++it) {
        int d = it * 256 + tid;
        xr[d] = x[(size_t)t * D_ + d];
    }
    __syncthreads();

    float a0 = 0.f, a1 = 0.f, a2 = 0.f, a3 = 0.f;
    #pragma unroll
    for (int it = 0; it < 4; ++it) {
        int d = it * 256 + tid;
        float xv = xr[d];
        float4 w = *(const float4*)(rgw + (size_t)d * 4);
        a0 += xv * w.x; a1 += xv * w.y; a2 += xv * w.z; a3 += xv * w.w;
    }
    float s0 = block_sum_(a0, red);
    float s1 = block_sum_(a1, red);
    float s2 = block_sum_(a2, red);
    float s3 = block_sum_(a3, red);
    if (tid == 0) {
        float r0 = sigmoidf_(s0 + rgb[0]);
        float r1 = sigmoidf_(s1 + rgb[1]);
        float r2 = sigmoidf_(s2 + rgb[2]);
        float r3 = sigmoidf_(s3 + rgb[3]);
        rgsh[0] = r0; rgsh[1] = r1; rgsh[2] = r2; rgsh[3] = r3;
        gs_out[(size_t)t * 4 + 0] = r0;
        gs_out[(size_t)t * 4 + 1] = r1;
        gs_out[(size_t)t * 4 + 2] = r2;
        gs_out[(size_t)t * 4 + 3] = r3;
    }
    __syncthreads();
    float factor = 1.0f + 0.025f * (rgsh[0] + rgsh[1] + rgsh[2] + rgsh[3]);

    float sm = 0.f, sq = 0.f;
    float vals[4];
    #pragma unroll
    for (int it = 0; it < 4; ++it) {
        int d = it * 256 + tid;
        float v = xr[d] * factor;
        vals[it] = v;
        xm[(size_t)t * D_ + d] = v;
        sm += v; sq += v * v;
    }
    float mean = block_sum_(sm, red) * (1.0f / D_);
    float msq  = block_sum_(sq, red) * (1.0f / D_);
    float rstd = rsqrtf(msq - mean * mean + 1e-5f);
    #pragma unroll
    for (int it = 0; it < 4; ++it) {
        int d = it * 256 + tid;
        ain[(size_t)t * D_ + d] = (vals[it] - mean) * rstd * g[d] + b[d];
    }
}

// ---------------------------------------------------------------------------
// plain LayerNorm over rows of D_  (one block per token row)
// ---------------------------------------------------------------------------
__global__ __launch_bounds__(256) void ln_k(
    const float* __restrict__ in, const float* __restrict__ g,
    const float* __restrict__ b, float* __restrict__ outp)
{
    int t = blockIdx.x, tid = threadIdx.x;
    __shared__ float red[256];
    float s1 = 0.f, s2 = 0.f;
    float vals[4];
    #pragma unroll
    for (int it = 0; it < 4; ++it) {
        int d = it * 256 + tid;
        float v = in[(size_t)t * D_ + d];
        vals[it] = v; s1 += v; s2 += v * v;
    }
    float mean = block_sum_(s1, red) * (1.0f / D_);
    float msq  = block_sum_(s2, red) * (1.0f / D_);
    float rstd = rsqrtf(msq - mean * mean + 1e-5f);
    #pragma unroll
    for (int it = 0; it < 4; ++it) {
        int d = it * 256 + tid;
        outp[(size_t)t * D_ + d] = (vals[it] - mean) * rstd * g[d] + b[d];
    }
}

// ---------------------------------------------------------------------------
// f32 GEMM  C[M,N] = act(A[M,K] @ W[K,N] + bias) (+ resid)
// 64x64 tile, BK=16, 256 threads, 4x4 per thread.
// act: 0 none, 1 exact GELU, 2 tanh(scale*z)
// ---------------------------------------------------------------------------
__global__ __launch_bounds__(256) void gemm_nn_k(
    const float* __restrict__ A, const float* __restrict__ W,
    const float* __restrict__ bias, const float* __restrict__ resid,
    float* __restrict__ C, int M, int N, int K,
    int act, const float* __restrict__ scale_ptr)
{
    __shared__ float As[16][65];
    __shared__ float Bs[16][64];
    const int tid = threadIdx.x;
    const int bm = blockIdx.y * 64;
    const int bn = blockIdx.x * 64;
    const int tx = tid & 15, ty = tid >> 4;
    const int ar = tid >> 2, ac = (tid & 3) << 2;
    const int br = tid >> 4, bc = (tid & 15) << 2;
    float acc[4][4] = {};

    for (int k0 = 0; k0 < K; k0 += 16) {
        float4 av = *(const float4*)(A + (size_t)(bm + ar) * K + k0 + ac);
        As[ac + 0][ar] = av.x; As[ac + 1][ar] = av.y;
        As[ac + 2][ar] = av.z; As[ac + 3][ar] = av.w;

        const float* wrow = W + (size_t)(k0 + br) * N;
        int ncol = bn + bc;
        float4 bv;
        if (ncol + 3 < N) {
            bv = *(const float4*)(wrow + ncol);
        } else {
            bv.x = (ncol + 0 < N) ? wrow[ncol + 0] : 0.f;
            bv.y = (ncol + 1 < N) ? wrow[ncol + 1] : 0.f;
            bv.z = (ncol + 2 < N) ? wrow[ncol + 2] : 0.f;
            bv.w = (ncol + 3 < N) ? wrow[ncol + 3] : 0.f;
        }
        *(float4*)(&Bs[br][bc]) = bv;
        __syncthreads();

        #pragma unroll
        for (int kk = 0; kk < 16; ++kk) {
            float a0 = As[kk][ty * 4 + 0];
            float a1 = As[kk][ty * 4 + 1];
            float a2 = As[kk][ty * 4 + 2];
            float a3 = As[kk][ty * 4 + 3];
            float4 bq = *(const float4*)(&Bs[kk][tx * 4]);
            acc[0][0] += a0 * bq.x; acc[0][1] += a0 * bq.y; acc[0][2] += a0 * bq.z; acc[0][3] += a0 * bq.w;
            acc[1][0] += a1 * bq.x; acc[1][1] += a1 * bq.y; acc[1][2] += a1 * bq.z; acc[1][3] += a1 * bq.w;
            acc[2][0] += a2 * bq.x; acc[2][1] += a2 * bq.y; acc[2][2] += a2 * bq.z; acc[2][3] += a2 * bq.w;
            acc[3][0] += a3 * bq.x; acc[3][1] += a3 * bq.y; acc[3][2] += a3 * bq.z; acc[3][3] += a3 * bq.w;
        }
        __syncthreads();
    }

    float scale = scale_ptr ? scale_ptr[0] : 1.0f;
    #pragma unroll
    for (int i = 0; i < 4; ++i) {
        int row = bm + ty * 4 + i;
        #pragma unroll
        for (int j = 0; j < 4; ++j) {
            int col = bn + tx * 4 + j;
            if (col < N) {
                float v = acc[i][j];
                if (bias) v += bias[col];
                if (act == 1)      v = gelu_exact_(v);
                else if (act == 2) v = tanhf(scale * v);
                if (resid) v += resid[(size_t)row * N + col];
                C[(size_t)row * N + col] = v;
            }
        }
    }
}

// ---------------------------------------------------------------------------
// f32 GEMM-NT  C[M,N] = A[M,K] @ Wt[N,K]^T   (for tied head: Wt = embed)
// ---------------------------------------------------------------------------
__global__ __launch_bounds__(256) void gemm_nt_k(
    const float* __restrict__ A, const float* __restrict__ Wt,
    float* __restrict__ C, int M, int N, int K)
{
    __shared__ float As[16][65];
    __shared__ float Bs[16][65];
    const int tid = threadIdx.x;
    const int bm = blockIdx.y * 64;
    const int bn = blockIdx.x * 64;
    const int tx = tid & 15, ty = tid >> 4;
    const int ar = tid >> 2, ac = (tid & 3) << 2;
    const int cc = tid >> 2, r4 = (tid & 3) << 2;
    float acc[4][4] = {};

    for (int k0 = 0; k0 < K; k0 += 16) {
        float4 av = *(const float4*)(A + (size_t)(bm + ar) * K + k0 + ac);
        As[ac + 0][ar] = av.x; As[ac + 1][ar] = av.y;
        As[ac + 2][ar] = av.z; As[ac + 3][ar] = av.w;

        float4 bv = make_float4(0.f, 0.f, 0.f, 0.f);
        int ncol = bn + cc;
        if (ncol < N) bv = *(const float4*)(Wt + (size_t)ncol * K + k0 + r4);
        Bs[r4 + 0][cc] = bv.x; Bs[r4 + 1][cc] = bv.y;
        Bs[r4 + 2][cc] = bv.z; Bs[r4 + 3][cc] = bv.w;
        __syncthreads();

        #pragma unroll
        for (int kk = 0; kk < 16; ++kk) {
            float a0 = As[kk][ty * 4 + 0];
            float a1 = As[kk][ty * 4 + 1];
            float a2 = As[kk][ty * 4 + 2];
            float a3 = As[kk][ty * 4 + 3];
            float b0 = Bs[kk][tx * 4 + 0];
            float b1 = Bs[kk][tx * 4 + 1];
            float b2 = Bs[kk][tx * 4 + 2];
            float b3 = Bs[kk][tx * 4 + 3];
            acc[0][0] += a0 * b0; acc[0][1] += a0 * b1; acc[0][2] += a0 * b2; acc[0][3] += a0 * b3;
            acc[1][0] += a1 * b0; acc[1][1] += a1 * b1; acc[1][2] += a1 * b2; acc[1][3] += a1 * b3;
            acc[2][0] += a2 * b0; acc[2][1] += a2 * b1; acc[2][2] += a2 * b2; acc[2][3] += a2 * b3;
            acc[3][0] += a3 * b0; acc[3][1] += a3 * b1; acc[3][2] += a3 * b2; acc[3][3] += a3 * b3;
        }
        __syncthreads();
    }

    #pragma unroll
    for (int i = 0; i < 4; ++i) {
        int row = bm + ty * 4 + i;
        #pragma unroll
        for (int j = 0; j < 4; ++j) {
            int col = bn + tx * 4 + j;
            if (col < N) C[(size_t)row * N + col] = acc[i][j];
        }
    }
}

// ---------------------------------------------------------------------------
// attention: one block per (lq, h, b). scores row in LDS, exact softmax.
// qkv rows: [BL, 3072] with q at col h*64+d, k at 1024+h*64+d, v at 2048+...
// ---------------------------------------------------------------------------
__global__ __launch_bounds__(256) void attn_k(
    const float* __restrict__ qkv, const float* __restrict__ pv,
    const float* __restrict__ res_scale_p, float* __restrict__ o)
{
    int lq = blockIdx.x, h = blockIdx.y, b = blockIdx.z;
    int tid = threadIdx.x;
    int tq = b * L_ + lq;

    __shared__ float qs[DH_];
    __shared__ float sc[L_];
    __shared__ float red[256];
    __shared__ float ored[256];
    __shared__ float pvq_s;

    if (tid < DH_) qs[tid] = qkv[(size_t)tq * 3072 + h * DH_ + tid];
    if (tid == 0) pvq_s = pv[(size_t)tq * H_ + h];
    __syncthreads();
    float rs = res_scale_p[0];
    float pvq = pvq_s;

    float lmax = -1e30f;
    #pragma unroll
    for (int it = 0; it < 4; ++it) {
        int m = it * 256 + tid;
        const float* kr = qkv + (size_t)(b * L_ + m) * 3072 + 1024 + h * DH_;
        float dot = 0.f;
        #pragma unroll
        for (int d4 = 0; d4 < 16; ++d4) {
            float4 kv = *(const float4*)(kr + d4 * 4);
            dot += qs[d4 * 4 + 0] * kv.x + qs[d4 * 4 + 1] * kv.y
                 + qs[d4 * 4 + 2] * kv.z + qs[d4 * 4 + 3] * kv.w;
        }
        float pd = pvq - pv[(size_t)(b * L_ + m) * H_ + h];
        float s = dot * 0.125f - rs * pd * pd;
        sc[m] = s;
        lmax = fmaxf(lmax, s);
    }
    float gmax = block_max_(lmax, red);

    float lsum = 0.f;
    #pragma unroll
    for (int it = 0; it < 4; ++it) {
        int m = it * 256 + tid;
        float p = expf(sc[m] - gmax);
        sc[m] = p;
        lsum += p;
    }
    float inv = 1.0f / block_sum_(lsum, red);
    __syncthreads();

    int d = tid & 63, chunk = tid >> 6;
    float acc = 0.f;
    int m0 = chunk * 256;
    for (int m = m0; m < m0 + 256; ++m) {
        acc += sc[m] * qkv[(size_t)(b * L_ + m) * 3072 + 2048 + h * DH_ + d];
    }
    ored[tid] = acc;
    __syncthreads();
    if (tid < DH_) {
        float v = (ored[tid] + ored[tid + 64] + ored[tid + 128] + ored[tid + 192]) * inv;
        o[(size_t)tq * D_ + h * DH_ + d] = v;
    }
}

// ---------------------------------------------------------------------------
// boundary second layer: ss[t] = sigmoid(dot(h[t], w2) + b2). block per token.
// ---------------------------------------------------------------------------
__global__ __launch_bounds__(256) void bnd2_k(
    const float* __restrict__ hbuf, const float* __restrict__ w2,
    const float* __restrict__ b2, float* __restrict__ ss_out)
{
    int t = blockIdx.x, tid = threadIdx.x;
    __shared__ float red[256];
    float acc = 0.f;
    #pragma unroll
    for (int it = 0; it < 2; ++it) {
        int d = it * 256 + tid;
        acc += hbuf[(size_t)t * HID_ + d] * w2[d];
    }
    float s = block_sum_(acc, red);
    if (tid == 0) ss_out[t] = sigmoidf_(s + b2[0]);
}

// ---------------------------------------------------------------------------
// grammar/shock means over layers
// ---------------------------------------------------------------------------
__global__ __launch_bounds__(256) void means_k(
    const float* __restrict__ gs, const float* __restrict__ ss,
    float* __restrict__ gsm, float* __restrict__ ssm)
{
    int i = blockIdx.x * 256 + threadIdx.x;
    if (i < BL_ * 4) {
        float s = 0.f;
        #pragma unroll
        for (int l = 0; l < NLAYER; ++l) s += gs[(size_t)l * BL_ * 4 + i];
        gsm[i] = s * (1.0f / NLAYER);
    }
    if (i < BL_) {
        float s = 0.f;
        #pragma unroll
        for (int l = 0; l < NLAYER; ++l) s += ss[(size_t)l * BL_ + i];
        ssm[i] = s * (1.0f / NLAYER);
    }
}

// ---------------------------------------------------------------------------
// launcher
// ---------------------------------------------------------------------------
extern "C" void kernel_launch(void* const* d_in, const int* in_sizes, int n_in,
                              void* d_out, int out_size, void* d_ws, size_t ws_size,
                              hipStream_t stream) {
    const int*   ids       = (const int*)  d_in[0];
    const float* embed     = (const float*)d_in[1];
    const float* pos_enc   = (const float*)d_in[2];
    const float* rg_w      = (const float*)d_in[3];
    const float* rg_b      = (const float*)d_in[4];
    const float* qkv_w     = (const float*)d_in[5];
    const float* qkv_b     = (const float*)d_in[6];
    const float* out_w     = (const float*)d_in[7];
    const float* out_b     = (const float*)d_in[8];
    const float* ph_w      = (const float*)d_in[9];
    const float* ph_b      = (const float*)d_in[10];
    const float* res_scale = (const float*)d_in[11];
    const float* ph_scale  = (const float*)d_in[12];
    const float* ff1_w     = (const float*)d_in[13];
    const float* ff1_b     = (const float*)d_in[14];
    const float* ff2_w     = (const float*)d_in[15];
    const float* ff2_b     = (const float*)d_in[16];
    const float* n1_g      = (const float*)d_in[17];
    const float* n1_b      = (const float*)d_in[18];
    const float* n2_g      = (const float*)d_in[19];
    const float* n2_b      = (const float*)d_in[20];
    const float* bnd_w1    = (const float*)d_in[21];
    const float* bnd_b1    = (const float*)d_in[22];
    const float* bnd_w2    = (const float*)d_in[23];
    const float* bnd_b2    = (const float*)d_in[24];
    const float* fn_g      = (const float*)d_in[25];
    const float* fn_b      = (const float*)d_in[26];

    float* out = (float*)d_out;
    float* ws  = (float*)d_ws;

    // workspace layout (floats). ffh aliases the dead qkv+attn_o region.
    const size_t M1 = 1024 * 1024;
    float* x    = ws;                    // 2M
    float* xm   = ws + 2 * M1;           // 2M
    float* ain  = ws + 4 * M1;           // 2M
    float* qkv  = ws + 6 * M1;           // 6M
    float* ao   = ws + 12 * M1;          // 2M
    float* ffh  = ws + 6 * M1;           // 8M (aliases qkv+ao, both dead by FF1)
    float* bndh = ws + 14 * M1;          // 1M
    float* pvb  = ws + 15 * M1;          // 32K
    // total: ~15.04M floats = ~60 MB

    // output offsets (floats, concatenated return order)
    const size_t o_logits = 0;
    const size_t o_x      = (size_t)BL_ * V_;
    const size_t o_gsm    = o_x + (size_t)BL_ * D_;
    const size_t o_ssm    = o_gsm + (size_t)BL_ * 4;
    const size_t o_gs     = o_ssm + (size_t)BL_;
    const size_t o_ss     = o_gs + (size_t)NLAYER * BL_ * 4;

    embed_k<<<BL_, 256, 0, stream>>>(ids, embed, pos_enc, x);

    for (int i = 0; i < NLAYER; ++i) {
        rg_xm_ln_k<<<BL_, 256, 0, stream>>>(
            x, rg_w + (size_t)i * D_ * 4, rg_b + (size_t)i * 4,
            n1_g + (size_t)i * D_, n1_b + (size_t)i * D_,
            xm, ain, out + o_gs + (size_t)i * BL_ * 4);

        dim3 gq(3 * D_ / 64, BL_ / 64);
        gemm_nn_k<<<gq, 256, 0, stream>>>(
            ain, qkv_w + (size_t)i * D_ * 3 * D_, qkv_b + (size_t)i * 3 * D_,
            nullptr, qkv, BL_, 3 * D_, D_, 0, nullptr);

        dim3 gp(1, BL_ / 64);
        gemm_nn_k<<<gp, 256, 0, stream>>>(
            ain, ph_w + (size_t)i * D_ * H_, ph_b + (size_t)i * H_,
            nullptr, pvb, BL_, H_, D_, 2, ph_scale + i);

        dim3 ga(L_, H_, B_);
        attn_k<<<ga, 256, 0, stream>>>(qkv, pvb, res_scale + i, ao);

        dim3 go(D_ / 64, BL_ / 64);
        gemm_nn_k<<<go, 256, 0, stream>>>(
            ao, out_w + (size_t)i * D_ * D_, out_b + (size_t)i * D_,
            xm, x, BL_, D_, D_, 0, nullptr);

        ln_k<<<BL_, 256, 0, stream>>>(x, n2_g + (size_t)i * D_, n2_b + (size_t)i * D_, ain);

        dim3 gf1(4 * D_ / 64, BL_ / 64);
        gemm_nn_k<<<gf1, 256, 0, stream>>>(
            ain, ff1_w + (size_t)i * D_ * 4 * D_, ff1_b + (size_t)i * 4 * D_,
            nullptr, ffh, BL_, 4 * D_, D_, 1, nullptr);

        dim3 gf2(D_ / 64, BL_ / 64);
        gemm_nn_k<<<gf2, 256, 0, stream>>>(
            ffh, ff2_w + (size_t)i * 4 * D_ * D_, ff2_b + (size_t)i * D_,
            x, x, BL_, D_, 4 * D_, 0, nullptr);

        dim3 gb1(HID_ / 64, BL_ / 64);
        gemm_nn_k<<<gb1, 256, 0, stream>>>(
            x, bnd_w1, bnd_b1, nullptr, bndh, BL_, HID_, D_, 2, nullptr);

        bnd2_k<<<BL_, 256, 0, stream>>>(bndh, bnd_w2, bnd_b2, out + o_ss + (size_t)i * BL_);
    }

    ln_k<<<BL_, 256, 0, stream>>>(x, fn_g, fn_b, out + o_x);

    dim3 gl((V_ + 63) / 64, BL_ / 64);
    gemm_nt_k<<<gl, 256, 0, stream>>>(out + o_x, embed, out + o_logits, BL_, V_, D_);

    means_k<<<(BL_ * 4 + 255) / 256, 256, 0, stream>>>(
        out + o_gs, out + o_ss, out + o_gsm, out + o_ssm);
}